// Round 3
// baseline (328.942 us; speedup 1.0000x reference)
//
#include <hip/hip_runtime.h>
#include <math.h>

#define L_MAX 2048
#define BATCH 64
#define DIM   256
#define CCH   512
#define ROWSTRIDE (BATCH * DIM)   // floats between consecutive l at fixed b
#define GRP   4                   // rows per pipeline group

// ws layout (floats):
#define HQ_OFF   0          // 64*256  = 16384
#define WF_OFF   16384      // 3*256   = 768
#define SUMS_OFF 17152      // 64*32 (one cache line per b) = 2048
#define HARD_OFF 19200      // 2048*64 = 131072
#define PART_OFF 150272     // 32*64*256 = 524288
#define SUMS_STRIDE 32

__device__ __forceinline__ float fast_tanh(float x) {
    float ax = fabsf(x);
    float e  = __expf(2.0f * ax);                       // inf for big ax -> r=1
    float r  = 1.0f - 2.0f * __builtin_amdgcn_rcpf(e + 1.0f);
    return copysignf(r, x);
}

// Async global->LDS, 16B per lane. LDS dest is wave-uniform base + lane*16
// (hardware adds the lane offset); global src is per-lane (must include d0).
__device__ __forceinline__ void gload16(const float* g, float* l) {
    __builtin_amdgcn_global_load_lds(
        (const __attribute__((address_space(1))) void*)g,
        (__attribute__((address_space(3))) void*)l,
        16, 0, 0);
}

// Kernel A: hq[b][d] = sum_k ht_query[b][k]*W_query[d][k]
//           wf[j][d] = sum_c W_conv[c][0][j]*W_att_past[d][c]
//           block 0 additionally zeroes sums[].
__global__ __launch_bounds__(256) void prep_kernel(
    const float* __restrict__ ht_query, const float* __restrict__ W_query,
    const float* __restrict__ W_conv,   const float* __restrict__ W_att_past,
    float* __restrict__ hq, float* __restrict__ wf, float* __restrict__ sums) {
    int t   = threadIdx.x;
    int blk = blockIdx.x;
    if (blk == 0 && t < BATCH) sums[t * SUMS_STRIDE] = 0.f;
    __shared__ float q[DIM];
    if (blk < BATCH) {
        q[t] = ht_query[blk * DIM + t];
        __syncthreads();
        const float4* wrow = (const float4*)(W_query + t * DIM);
        float acc = 0.f;
        #pragma unroll 8
        for (int k = 0; k < DIM / 4; k++) {
            float4 wv = wrow[k];
            acc += q[4*k] * wv.x + q[4*k+1] * wv.y + q[4*k+2] * wv.z + q[4*k+3] * wv.w;
        }
        hq[blk * DIM + t] = acc;
    } else {
        int j = blk - BATCH;
        const float4* wrow = (const float4*)(W_att_past + t * CCH);
        float acc = 0.f;
        #pragma unroll 8
        for (int c = 0; c < CCH / 4; c++) {
            float4 wv = wrow[c];
            acc += W_conv[(4*c  ) * 3 + j] * wv.x + W_conv[(4*c+1) * 3 + j] * wv.y
                 + W_conv[(4*c+2) * 3 + j] * wv.z + W_conv[(4*c+3) * 3 + j] * wv.w;
        }
        wf[j * DIM + t] = acc;
    }
}

// Fused kernel, v3: per-wave counted-vmcnt pipeline (T4), no mid-loop barriers.
//
// Round-2 post-mortem: v2 still drained vmcnt(0) at a block barrier each
// subtile, with the h-conditional val DMA issued immediately before its own
// drain -> one fully-exposed latency per subtile, same 84us / 17% BW as v0.
// Fix: (1) unconditional val loads (acc += v*h, h==0 exact) so key+val of a
// group are independent and issuable 2 groups ahead; (2) each wave's LDS is
// private, so ALL mid-loop __syncthreads are removed; DMA completion is
// awaited per-wave with counted s_waitcnt vmcnt(8) -- the next group's 8
// DMAs stay in flight across every wait (never drain to 0 in the loop).
// Prologue pins its scalar loads with vmcnt(0) so the counted waits see only
// DMA ops. 2 blocks/CU (70KB LDS) x 4 waves x up to 16KB DMA in flight.
__global__ __launch_bounds__(256) void fused_kernel(
    const float* __restrict__ ctx_key, const float* __restrict__ ctx_val,
    const float* __restrict__ ctx_mask, const float* __restrict__ att_past,
    const float* __restrict__ hq, const float* __restrict__ wf,
    const float* __restrict__ b_att_past, const float* __restrict__ W_attn,
    const float* __restrict__ b_attn,
    float* __restrict__ hard_raw, float* __restrict__ sums,
    float* __restrict__ part) {
    // [wave][buf][key4|val4][DIM] : 4 * 2 * 8 * 256 floats = 64KB
    __shared__ __align__(16) float stage[4 * 2 * 2 * GRP * DIM];
    __shared__ float red[4 * DIM];
    __shared__ float c4[4];

    int b     = blockIdx.x & 63;
    int chunk = blockIdx.x >> 6;
    int w     = threadIdx.x >> 6;
    int lane  = threadIdx.x & 63;
    int d0    = lane << 2;
    int l0w   = chunk * 64 + w * 16;   // this wave's first row

    float* wstage = stage + w * (2 * 2 * GRP * DIM);

    float4 hq4 = *(const float4*)(hq + b * DIM + d0);
    float4 bp  = *(const float4*)(b_att_past + d0);
    hq4.x += bp.x; hq4.y += bp.y; hq4.z += bp.z; hq4.w += bp.w;
    float4 w0  = *(const float4*)(wf + d0);
    float4 w1  = *(const float4*)(wf + DIM + d0);
    float4 w2  = *(const float4*)(wf + 2 * DIM + d0);
    float4 wa  = *(const float4*)(W_attn + d0);
    float battn = b_attn[0];
    const float* apb = att_past + b * L_MAX;

    // att_past window [l0w-1, l0w+16]: ap[i] = apb[l0w-1+i]
    float ap[18];
    {
        float4 t0 = *(const float4*)(apb + l0w);
        float4 t1 = *(const float4*)(apb + l0w + 4);
        float4 t2 = *(const float4*)(apb + l0w + 8);
        float4 t3 = *(const float4*)(apb + l0w + 12);
        ap[1]=t0.x; ap[2]=t0.y; ap[3]=t0.z; ap[4]=t0.w;
        ap[5]=t1.x; ap[6]=t1.y; ap[7]=t1.z; ap[8]=t1.w;
        ap[9]=t2.x; ap[10]=t2.y; ap[11]=t2.z; ap[12]=t2.w;
        ap[13]=t3.x; ap[14]=t3.y; ap[15]=t3.z; ap[16]=t3.w;
        ap[0]  = (l0w > 0)          ? apb[l0w - 1]  : 0.f;
        ap[17] = (l0w + 16 < L_MAX) ? apb[l0w + 16] : 0.f;
    }

    // masks for this wave's 16 rows
    float m16[16];
    #pragma unroll
    for (int j = 0; j < 16; j++)
        m16[j] = ctx_mask[(l0w + j) * BATCH + b];

    // Pin: all compiler-emitted prologue loads complete here, so the counted
    // waits below see ONLY our DMA ops in vmcnt. "memory" clobber keeps any
    // load from crossing this point in either direction.
    asm volatile("s_waitcnt vmcnt(0)" ::: "memory");

    float h16[16];
    float cnt = 0.f;
    float4 acc = make_float4(0.f, 0.f, 0.f, 0.f);

    // issue key+val rows of group g (4 rows each stream, 8 DMAs) into buf g&1
    #define ISSUE(g) do {                                                      \
        float* buf_ = wstage + ((g) & 1) * (2 * GRP * DIM);                    \
        _Pragma("unroll")                                                      \
        for (int j = 0; j < GRP; j++)                                          \
            gload16(ctx_key + (size_t)((l0w + (g) * GRP + j) * BATCH + b) * DIM + d0, \
                    buf_ + j * DIM);                                           \
        _Pragma("unroll")                                                      \
        for (int j = 0; j < GRP; j++)                                          \
            gload16(ctx_val + (size_t)((l0w + (g) * GRP + j) * BATCH + b) * DIM + d0, \
                    buf_ + (GRP + j) * DIM);                                   \
    } while (0)

    // wait for group g (leaving the next group's 8 DMAs in flight), compute
    // its scores, butterfly, h, and accumulate vals; then issue group g+2.
    #define STEP(g, WAITSTR) do {                                              \
        asm volatile("s_waitcnt " WAITSTR ::: "memory");                       \
        __builtin_amdgcn_sched_barrier(0);                                     \
        const float* buf_ = wstage + ((g) & 1) * (2 * GRP * DIM);              \
        float p[GRP];                                                          \
        _Pragma("unroll")                                                      \
        for (int j = 0; j < GRP; j++) {                                        \
            int r = (g) * GRP + j;                                             \
            float4 k = *(const float4*)(buf_ + j * DIM + d0);                  \
            float am = ap[r], a0 = ap[r + 1], a1 = ap[r + 2];                  \
            float x0 = k.x + hq4.x + am * w0.x + a0 * w1.x + a1 * w2.x;        \
            float x1 = k.y + hq4.y + am * w0.y + a0 * w1.y + a1 * w2.y;        \
            float x2 = k.z + hq4.z + am * w0.z + a0 * w1.z + a1 * w2.z;        \
            float x3 = k.w + hq4.w + am * w0.w + a0 * w1.w + a1 * w2.w;        \
            p[j] = fast_tanh(x0) * wa.x + fast_tanh(x1) * wa.y +               \
                   fast_tanh(x2) * wa.z + fast_tanh(x3) * wa.w;                \
        }                                                                      \
        _Pragma("unroll")                                                      \
        for (int off = 32; off > 0; off >>= 1) {                               \
            _Pragma("unroll")                                                  \
            for (int j = 0; j < GRP; j++)                                      \
                p[j] += __shfl_xor(p[j], off, 64);                             \
        }                                                                      \
        _Pragma("unroll")                                                      \
        for (int j = 0; j < GRP; j++) {                                        \
            int r = (g) * GRP + j;                                             \
            float hv = (p[j] + battn >= 0.f) ? m16[r] : 0.f;                   \
            h16[r] = hv; cnt += hv;                                            \
            float4 v = *(const float4*)(buf_ + (GRP + j) * DIM + d0);          \
            acc.x += v.x * hv; acc.y += v.y * hv;                              \
            acc.z += v.z * hv; acc.w += v.w * hv;                              \
        }                                                                      \
        if ((g) < 2) ISSUE((g) + 2);                                           \
    } while (0)

    ISSUE(0);
    ISSUE(1);
    STEP(0, "vmcnt(8)");
    STEP(1, "vmcnt(8)");
    STEP(2, "vmcnt(8)");
    STEP(3, "vmcnt(0)");

    #undef STEP
    #undef ISSUE

    // hard_raw writes (unnormalized), one store stream from lane 0
    if (lane == 0) {
        #pragma unroll
        for (int j = 0; j < 16; j++)
            hard_raw[(l0w + j) * BATCH + b] = h16[j];
    }

    // cross-wave reduction of acc into part (only block-wide sync point)
    *(float4*)(red + w * DIM + d0) = acc;
    if (lane == 0) c4[w] = cnt;
    __syncthreads();
    int d = threadIdx.x;
    float sred = red[d] + red[DIM + d] + red[2 * DIM + d] + red[3 * DIM + d];
    part[(size_t)(chunk * BATCH + b) * DIM + d] = sred;
    if (threadIdx.x == 0)
        atomicAdd(&sums[b * SUMS_STRIDE], c4[0] + c4[1] + c4[2] + c4[3]);
}

// Tail: blocks 0..63   -> ct[b][d] = (sum_chunk part) / (Z_b+1e-10)
//       blocks 64..191 -> out_hard[l][b] = hard_raw[l][b] / (Z_b+1e-10)
__global__ __launch_bounds__(256) void tail_kernel(
    const float* __restrict__ part, const float* __restrict__ hard_raw,
    const float* __restrict__ sums,
    float* __restrict__ ct, float* __restrict__ out_hard) {
    if (blockIdx.x < BATCH) {
        int b = blockIdx.x;
        int d = threadIdx.x;
        float s = 0.f;
        #pragma unroll 8
        for (int c = 0; c < 32; c++)
            s += part[(size_t)(c * BATCH + b) * DIM + d];
        float invZ = 1.0f / (sums[b * SUMS_STRIDE] + 1e-10f);
        ct[b * DIM + d] = s * invZ;
    } else {
        int i = (blockIdx.x - BATCH) * 256 + threadIdx.x;   // 4 elems each
        float4 h = *(const float4*)(hard_raw + (size_t)i * 4);
        int b0 = (i * 4) & 63;
        float4 o;
        o.x = h.x / (sums[(b0 + 0) * SUMS_STRIDE] + 1e-10f);
        o.y = h.y / (sums[(b0 + 1) * SUMS_STRIDE] + 1e-10f);
        o.z = h.z / (sums[(b0 + 2) * SUMS_STRIDE] + 1e-10f);
        o.w = h.w / (sums[(b0 + 3) * SUMS_STRIDE] + 1e-10f);
        *(float4*)(out_hard + (size_t)i * 4) = o;
    }
}

extern "C" void kernel_launch(void* const* d_in, const int* in_sizes, int n_in,
                              void* d_out, int out_size, void* d_ws, size_t ws_size,
                              hipStream_t stream) {
    const float* ctx_val    = (const float*)d_in[0];
    const float* ctx_key    = (const float*)d_in[1];
    const float* ctx_mask   = (const float*)d_in[2];
    const float* att_past   = (const float*)d_in[3];
    const float* ht_query   = (const float*)d_in[4];
    const float* W_conv     = (const float*)d_in[5];
    const float* W_query    = (const float*)d_in[6];
    const float* W_att_past = (const float*)d_in[7];
    const float* b_att_past = (const float*)d_in[8];
    const float* W_attn     = (const float*)d_in[9];
    const float* b_attn     = (const float*)d_in[10];

    float* ws   = (float*)d_ws;
    float* hq   = ws + HQ_OFF;
    float* wf   = ws + WF_OFF;
    float* sums = ws + SUMS_OFF;
    float* hard = ws + HARD_OFF;
    float* part = ws + PART_OFF;

    float* out_ct   = (float*)d_out;                 // (64,256)
    float* out_hard = (float*)d_out + BATCH * DIM;   // (2048,64)

    prep_kernel<<<BATCH + 3, 256, 0, stream>>>(
        ht_query, W_query, W_conv, W_att_past, hq, wf, sums);

    fused_kernel<<<BATCH * 32, 256, 0, stream>>>(
        ctx_key, ctx_val, ctx_mask, att_past, hq, wf, b_att_past, W_attn, b_attn,
        hard, sums, part);

    tail_kernel<<<BATCH + 128, 256, 0, stream>>>(part, hard, sums, out_ct, out_hard);
}

// Round 4
// 313.572 us; speedup vs baseline: 1.0490x; 1.0490x over previous
//
#include <hip/hip_runtime.h>
#include <math.h>

#define L_MAX 2048
#define BATCH 64
#define DIM   256
#define CCH   512
#define ROWSTRIDE (BATCH * DIM)   // floats between consecutive l at fixed b
#define GRP   4                   // rows per pipeline group

// ws layout (floats):
#define HQ_OFF   0          // 64*256  = 16384
#define WF_OFF   16384      // 3*256   = 768
#define SUMS_OFF 17152      // 64*32 (one cache line per b) = 2048
#define HARD_OFF 19200      // 2048*64 = 131072
#define PART_OFF 150272     // 32*64*256 = 524288
#define SUMS_STRIDE 32

__device__ __forceinline__ float fast_tanh(float x) {
    float ax = fabsf(x);
    float e  = __expf(2.0f * ax);                       // inf for big ax -> r=1
    float r  = 1.0f - 2.0f * __builtin_amdgcn_rcpf(e + 1.0f);
    return copysignf(r, x);
}

// Async global->LDS, 16B per lane, NON-TEMPORAL (aux=2 = NT cpol bit on
// gfx940+). key/val have zero intra-dispatch reuse and the 250MB input set
// sits at L3 capacity: letting these streams churn the Infinity Cache gives
// a ~50%-thrashed L3 whose hit/miss interleave fragments the HBM burst
// stream (round-3 fit: 6.3 TB/s marginal + ~54us fixed cost). NT = evict-
// first: stop polluting L3, make the HBM side a clean sequential miss
// stream. This is the ONLY change vs round 3 (single-variable A/B).
__device__ __forceinline__ void gload16(const float* g, float* l) {
    __builtin_amdgcn_global_load_lds(
        (const __attribute__((address_space(1))) void*)g,
        (__attribute__((address_space(3))) void*)l,
        16, 0, 2 /* NT */);
}

// Kernel A: hq[b][d] = sum_k ht_query[b][k]*W_query[d][k]
//           wf[j][d] = sum_c W_conv[c][0][j]*W_att_past[d][c]
//           block 0 additionally zeroes sums[].
__global__ __launch_bounds__(256) void prep_kernel(
    const float* __restrict__ ht_query, const float* __restrict__ W_query,
    const float* __restrict__ W_conv,   const float* __restrict__ W_att_past,
    float* __restrict__ hq, float* __restrict__ wf, float* __restrict__ sums) {
    int t   = threadIdx.x;
    int blk = blockIdx.x;
    if (blk == 0 && t < BATCH) sums[t * SUMS_STRIDE] = 0.f;
    __shared__ float q[DIM];
    if (blk < BATCH) {
        q[t] = ht_query[blk * DIM + t];
        __syncthreads();
        const float4* wrow = (const float4*)(W_query + t * DIM);
        float acc = 0.f;
        #pragma unroll 8
        for (int k = 0; k < DIM / 4; k++) {
            float4 wv = wrow[k];
            acc += q[4*k] * wv.x + q[4*k+1] * wv.y + q[4*k+2] * wv.z + q[4*k+3] * wv.w;
        }
        hq[blk * DIM + t] = acc;
    } else {
        int j = blk - BATCH;
        const float4* wrow = (const float4*)(W_att_past + t * CCH);
        float acc = 0.f;
        #pragma unroll 8
        for (int c = 0; c < CCH / 4; c++) {
            float4 wv = wrow[c];
            acc += W_conv[(4*c  ) * 3 + j] * wv.x + W_conv[(4*c+1) * 3 + j] * wv.y
                 + W_conv[(4*c+2) * 3 + j] * wv.z + W_conv[(4*c+3) * 3 + j] * wv.w;
        }
        wf[j * DIM + t] = acc;
    }
}

// Fused kernel, v4 = v3 + non-temporal key/val streams (see gload16).
// v3 structure: per-wave counted-vmcnt pipeline, no mid-loop barriers,
// unconditional val loads, wave-private LDS staging.
__global__ __launch_bounds__(256) void fused_kernel(
    const float* __restrict__ ctx_key, const float* __restrict__ ctx_val,
    const float* __restrict__ ctx_mask, const float* __restrict__ att_past,
    const float* __restrict__ hq, const float* __restrict__ wf,
    const float* __restrict__ b_att_past, const float* __restrict__ W_attn,
    const float* __restrict__ b_attn,
    float* __restrict__ hard_raw, float* __restrict__ sums,
    float* __restrict__ part) {
    // [wave][buf][key4|val4][DIM] : 4 * 2 * 8 * 256 floats = 64KB
    __shared__ __align__(16) float stage[4 * 2 * 2 * GRP * DIM];
    __shared__ float red[4 * DIM];
    __shared__ float c4[4];

    int b     = blockIdx.x & 63;
    int chunk = blockIdx.x >> 6;
    int w     = threadIdx.x >> 6;
    int lane  = threadIdx.x & 63;
    int d0    = lane << 2;
    int l0w   = chunk * 64 + w * 16;   // this wave's first row

    float* wstage = stage + w * (2 * 2 * GRP * DIM);

    float4 hq4 = *(const float4*)(hq + b * DIM + d0);
    float4 bp  = *(const float4*)(b_att_past + d0);
    hq4.x += bp.x; hq4.y += bp.y; hq4.z += bp.z; hq4.w += bp.w;
    float4 w0  = *(const float4*)(wf + d0);
    float4 w1  = *(const float4*)(wf + DIM + d0);
    float4 w2  = *(const float4*)(wf + 2 * DIM + d0);
    float4 wa  = *(const float4*)(W_attn + d0);
    float battn = b_attn[0];
    const float* apb = att_past + b * L_MAX;

    // att_past window [l0w-1, l0w+16]: ap[i] = apb[l0w-1+i]
    float ap[18];
    {
        float4 t0 = *(const float4*)(apb + l0w);
        float4 t1 = *(const float4*)(apb + l0w + 4);
        float4 t2 = *(const float4*)(apb + l0w + 8);
        float4 t3 = *(const float4*)(apb + l0w + 12);
        ap[1]=t0.x; ap[2]=t0.y; ap[3]=t0.z; ap[4]=t0.w;
        ap[5]=t1.x; ap[6]=t1.y; ap[7]=t1.z; ap[8]=t1.w;
        ap[9]=t2.x; ap[10]=t2.y; ap[11]=t2.z; ap[12]=t2.w;
        ap[13]=t3.x; ap[14]=t3.y; ap[15]=t3.z; ap[16]=t3.w;
        ap[0]  = (l0w > 0)          ? apb[l0w - 1]  : 0.f;
        ap[17] = (l0w + 16 < L_MAX) ? apb[l0w + 16] : 0.f;
    }

    // masks for this wave's 16 rows
    float m16[16];
    #pragma unroll
    for (int j = 0; j < 16; j++)
        m16[j] = ctx_mask[(l0w + j) * BATCH + b];

    // Pin: all compiler-emitted prologue loads complete here, so the counted
    // waits below see ONLY our DMA ops in vmcnt. "memory" clobber keeps any
    // load from crossing this point in either direction.
    asm volatile("s_waitcnt vmcnt(0)" ::: "memory");

    float h16[16];
    float cnt = 0.f;
    float4 acc = make_float4(0.f, 0.f, 0.f, 0.f);

    // issue key+val rows of group g (4 rows each stream, 8 DMAs) into buf g&1
    #define ISSUE(g) do {                                                      \
        float* buf_ = wstage + ((g) & 1) * (2 * GRP * DIM);                    \
        _Pragma("unroll")                                                      \
        for (int j = 0; j < GRP; j++)                                          \
            gload16(ctx_key + (size_t)((l0w + (g) * GRP + j) * BATCH + b) * DIM + d0, \
                    buf_ + j * DIM);                                           \
        _Pragma("unroll")                                                      \
        for (int j = 0; j < GRP; j++)                                          \
            gload16(ctx_val + (size_t)((l0w + (g) * GRP + j) * BATCH + b) * DIM + d0, \
                    buf_ + (GRP + j) * DIM);                                   \
    } while (0)

    // wait for group g (leaving the next group's 8 DMAs in flight), compute
    // its scores, butterfly, h, and accumulate vals; then issue group g+2.
    #define STEP(g, WAITSTR) do {                                              \
        asm volatile("s_waitcnt " WAITSTR ::: "memory");                       \
        __builtin_amdgcn_sched_barrier(0);                                     \
        const float* buf_ = wstage + ((g) & 1) * (2 * GRP * DIM);              \
        float p[GRP];                                                          \
        _Pragma("unroll")                                                      \
        for (int j = 0; j < GRP; j++) {                                        \
            int r = (g) * GRP + j;                                             \
            float4 k = *(const float4*)(buf_ + j * DIM + d0);                  \
            float am = ap[r], a0 = ap[r + 1], a1 = ap[r + 2];                  \
            float x0 = k.x + hq4.x + am * w0.x + a0 * w1.x + a1 * w2.x;        \
            float x1 = k.y + hq4.y + am * w0.y + a0 * w1.y + a1 * w2.y;        \
            float x2 = k.z + hq4.z + am * w0.z + a0 * w1.z + a1 * w2.z;        \
            float x3 = k.w + hq4.w + am * w0.w + a0 * w1.w + a1 * w2.w;        \
            p[j] = fast_tanh(x0) * wa.x + fast_tanh(x1) * wa.y +               \
                   fast_tanh(x2) * wa.z + fast_tanh(x3) * wa.w;                \
        }                                                                      \
        _Pragma("unroll")                                                      \
        for (int off = 32; off > 0; off >>= 1) {                               \
            _Pragma("unroll")                                                  \
            for (int j = 0; j < GRP; j++)                                      \
                p[j] += __shfl_xor(p[j], off, 64);                             \
        }                                                                      \
        _Pragma("unroll")                                                      \
        for (int j = 0; j < GRP; j++) {                                        \
            int r = (g) * GRP + j;                                             \
            float hv = (p[j] + battn >= 0.f) ? m16[r] : 0.f;                   \
            h16[r] = hv; cnt += hv;                                            \
            float4 v = *(const float4*)(buf_ + (GRP + j) * DIM + d0);          \
            acc.x += v.x * hv; acc.y += v.y * hv;                              \
            acc.z += v.z * hv; acc.w += v.w * hv;                              \
        }                                                                      \
        if ((g) < 2) ISSUE((g) + 2);                                           \
    } while (0)

    ISSUE(0);
    ISSUE(1);
    STEP(0, "vmcnt(8)");
    STEP(1, "vmcnt(8)");
    STEP(2, "vmcnt(8)");
    STEP(3, "vmcnt(0)");

    #undef STEP
    #undef ISSUE

    // hard_raw writes (unnormalized), one store stream from lane 0
    if (lane == 0) {
        #pragma unroll
        for (int j = 0; j < 16; j++)
            hard_raw[(l0w + j) * BATCH + b] = h16[j];
    }

    // cross-wave reduction of acc into part (only block-wide sync point)
    *(float4*)(red + w * DIM + d0) = acc;
    if (lane == 0) c4[w] = cnt;
    __syncthreads();
    int d = threadIdx.x;
    float sred = red[d] + red[DIM + d] + red[2 * DIM + d] + red[3 * DIM + d];
    part[(size_t)(chunk * BATCH + b) * DIM + d] = sred;
    if (threadIdx.x == 0)
        atomicAdd(&sums[b * SUMS_STRIDE], c4[0] + c4[1] + c4[2] + c4[3]);
}

// Tail: blocks 0..63   -> ct[b][d] = (sum_chunk part) / (Z_b+1e-10)
//       blocks 64..191 -> out_hard[l][b] = hard_raw[l][b] / (Z_b+1e-10)
__global__ __launch_bounds__(256) void tail_kernel(
    const float* __restrict__ part, const float* __restrict__ hard_raw,
    const float* __restrict__ sums,
    float* __restrict__ ct, float* __restrict__ out_hard) {
    if (blockIdx.x < BATCH) {
        int b = blockIdx.x;
        int d = threadIdx.x;
        float s = 0.f;
        #pragma unroll 8
        for (int c = 0; c < 32; c++)
            s += part[(size_t)(c * BATCH + b) * DIM + d];
        float invZ = 1.0f / (sums[b * SUMS_STRIDE] + 1e-10f);
        ct[b * DIM + d] = s * invZ;
    } else {
        int i = (blockIdx.x - BATCH) * 256 + threadIdx.x;   // 4 elems each
        float4 h = *(const float4*)(hard_raw + (size_t)i * 4);
        int b0 = (i * 4) & 63;
        float4 o;
        o.x = h.x / (sums[(b0 + 0) * SUMS_STRIDE] + 1e-10f);
        o.y = h.y / (sums[(b0 + 1) * SUMS_STRIDE] + 1e-10f);
        o.z = h.z / (sums[(b0 + 2) * SUMS_STRIDE] + 1e-10f);
        o.w = h.w / (sums[(b0 + 3) * SUMS_STRIDE] + 1e-10f);
        *(float4*)(out_hard + (size_t)i * 4) = o;
    }
}

extern "C" void kernel_launch(void* const* d_in, const int* in_sizes, int n_in,
                              void* d_out, int out_size, void* d_ws, size_t ws_size,
                              hipStream_t stream) {
    const float* ctx_val    = (const float*)d_in[0];
    const float* ctx_key    = (const float*)d_in[1];
    const float* ctx_mask   = (const float*)d_in[2];
    const float* att_past   = (const float*)d_in[3];
    const float* ht_query   = (const float*)d_in[4];
    const float* W_conv     = (const float*)d_in[5];
    const float* W_query    = (const float*)d_in[6];
    const float* W_att_past = (const float*)d_in[7];
    const float* b_att_past = (const float*)d_in[8];
    const float* W_attn     = (const float*)d_in[9];
    const float* b_attn     = (const float*)d_in[10];

    float* ws   = (float*)d_ws;
    float* hq   = ws + HQ_OFF;
    float* wf   = ws + WF_OFF;
    float* sums = ws + SUMS_OFF;
    float* hard = ws + HARD_OFF;
    float* part = ws + PART_OFF;

    float* out_ct   = (float*)d_out;                 // (64,256)
    float* out_hard = (float*)d_out + BATCH * DIM;   // (2048,64)

    prep_kernel<<<BATCH + 3, 256, 0, stream>>>(
        ht_query, W_query, W_conv, W_att_past, hq, wf, sums);

    fused_kernel<<<BATCH * 32, 256, 0, stream>>>(
        ctx_key, ctx_val, ctx_mask, att_past, hq, wf, b_att_past, W_attn, b_attn,
        hard, sums, part);

    tail_kernel<<<BATCH + 128, 256, 0, stream>>>(part, hard, sums, out_ct, out_hard);
}